// Round 1
// baseline (552.740 us; speedup 1.0000x reference)
//
#include <hip/hip_runtime.h>
#include <math.h>

// Problem constants
#define Tn 30
#define Bn 16384
#define Hn 100
#define Pn 7

// Tiling: gates padded 100->128 units => N=512 (32 n-tiles); K padded 100->128 (4 k-tiles of 32).
// 32 rows/block (grid 512) => LDS 54272 B/block => 2 blocks/CU (4 waves/SIMD) for latency hiding.
// 8 waves/block; wave w owns unit-block ag=w (16 units, all 4 gates); wave 7 is pure padding -> skipped.
// B-fragments (16/wave) live in registers; h double-buffered in LDS; 1 barrier/step.
#define ROWS 32           // rows per block
#define RGn 2             // row-groups of 16
#define KP 136            // h row pitch (ushorts); 272B -> 16B-aligned A-frag reads
#define RP 36             // gin2 row pitch (ushorts): 32 rows + 4 pad
#define NFRAG 128         // B-frags per matrix (32 nt x 4 kt)
#define FRAG_BYTES (NFRAG * 64 * 16)   // 131072 per matrix
#define WS_FRAG_OFF 4096
#define WS_W2_OFF (WS_FRAG_OFF + 3 * FRAG_BYTES)     // 28 W2 frags (7 ps x 4 kt)
#define HBUF_USH (ROWS * KP)                         // 4352
#define SMEM_BYTES (2 * HBUF_USH * 2 + 512 * RP * 2) // 17408 + 36864 = 54272

#define PACK_BLOCKS 103   // (3*128*64 + 28*64)/256

typedef __attribute__((ext_vector_type(8))) short short8;   // 8 bf16 (4 VGPRs)
typedef __attribute__((ext_vector_type(4))) float floatx4;  // MFMA C/D

__device__ __forceinline__ float rcp_(float v) { return __builtin_amdgcn_rcpf(v); }
__device__ __forceinline__ float sig_(float v) { return rcp_(1.0f + __expf(-v)); }
__device__ __forceinline__ float tanh_(float v) { return 1.0f - 2.0f * rcp_(__expf(2.0f * v) + 1.0f); }
__device__ __forceinline__ unsigned short f2bf(float v) {
    unsigned int u = __float_as_uint(v);
    return (unsigned short)((u + 0x7FFFu + ((u >> 16) & 1u)) >> 16);   // RNE
}

// One launch does both jobs:
//  blocks [0, PACK_BLOCKS): pack the 3 recurrent matrices (400x100) into bf16 B-frag layout
//    (gates padded to 128 units), plus W2 (7 x 700) into 7x4 B-frags with n = p.
//    B[k][n]: n = lane&15, k = (lane>>4)*8 + jj  (16x16x32 bf16 B mapping, HW-verified).
//  blocks [PACK_BLOCKS, PACK_BLOCKS+2): ws[0..399] = u1[j] = Wih1[j,:]·W1 (rank-1 FC1 fold);
//    ws[400..799] = Wih1[j,:]·b1 + bih1[j] + bhh1[j]
__global__ void setup_kernel(const float* __restrict__ W1,
                             const float* __restrict__ b1,
                             const float* __restrict__ Wih1,
                             const float* __restrict__ bih1,
                             const float* __restrict__ bhh1,
                             const float* __restrict__ Whh1,
                             const float* __restrict__ Wih2,
                             const float* __restrict__ Whh2,
                             const float* __restrict__ W2,
                             float* __restrict__ ws) {
    if (blockIdx.x >= PACK_BLOCKS) {
        int j = (blockIdx.x - PACK_BLOCKS) * 256 + threadIdx.x;
        if (j < 400) {
            float u = 0.f, w = 0.f;
            for (int k = 0; k < Hn; ++k) {
                float a = Wih1[j * Hn + k];
                u += a * W1[k];
                w += a * b1[k];
            }
            ws[j] = u;
            ws[400 + j] = w + bih1[j] + bhh1[j];
        }
        return;
    }
    int gid = blockIdx.x * 256 + threadIdx.x;   // 3*128*64 + 28*64 = 26368
    int lane = gid & 63;
    int l = lane & 15, q = lane >> 4;
    unsigned short hh[8];
    uint4 u;
    if (gid < 3 * NFRAG * 64) {
        int mat = gid / (NFRAG * 64);
        int f = (gid % (NFRAG * 64)) >> 6;
        int nt = f >> 2, kt = f & 3;
        int G = nt >> 3, ag = nt & 7;
        int j = ag * 16 + l;
        const float* W = (mat == 0) ? Whh1 : (mat == 1) ? Wih2 : Whh2;
        const float* wrow = W + (G * Hn + (j < Hn ? j : 0)) * Hn;
        int kbase = kt * 32 + q * 8;
#pragma unroll
        for (int jj = 0; jj < 8; ++jj) {
            int k = kbase + jj;
            hh[jj] = (j < Hn && k < Hn) ? f2bf(wrow[k]) : (unsigned short)0;
        }
        u.x = (unsigned)hh[0] | ((unsigned)hh[1] << 16);
        u.y = (unsigned)hh[2] | ((unsigned)hh[3] << 16);
        u.z = (unsigned)hh[4] | ((unsigned)hh[5] << 16);
        u.w = (unsigned)hh[6] | ((unsigned)hh[7] << 16);
        ((uint4*)((char*)ws + WS_FRAG_OFF + mat * FRAG_BYTES))[f * 64 + lane] = u;
    } else {
        int t = gid - 3 * NFRAG * 64;           // 0..1791
        int f = t >> 6;                         // 0..27 = ps*4 + kt
        int ps = f >> 2, kt = f & 3;
        int kbase = kt * 32 + q * 8;
#pragma unroll
        for (int jj = 0; jj < 8; ++jj) {
            int k = kbase + jj;
            hh[jj] = (l < Pn && k < Hn) ? f2bf(W2[l * (Pn * Hn) + ps * Hn + k])
                                        : (unsigned short)0;
        }
        u.x = (unsigned)hh[0] | ((unsigned)hh[1] << 16);
        u.y = (unsigned)hh[2] | ((unsigned)hh[3] << 16);
        u.z = (unsigned)hh[4] | ((unsigned)hh[5] << 16);
        u.w = (unsigned)hh[6] | ((unsigned)hh[7] << 16);
        ((uint4*)((char*)ws + WS_W2_OFF))[f * 64 + lane] = u;
    }
}

__global__ __launch_bounds__(512, 4) void lstm_fused(
    const float* __restrict__ x,     // (T,B)
    const float* __restrict__ ws,    // u1/wc1 + packed frags
    const float* __restrict__ bih2,
    const float* __restrict__ bhh2,
    const float* __restrict__ b2,    // (7,)
    float* __restrict__ out)         // (B,7)
{
    extern __shared__ unsigned short sm[];
    unsigned short* hb0 = sm;                   // h double buffer [row ROWS][k KP]
    unsigned short* hb1 = sm + HBUF_USH;
    unsigned short* g2 = sm + 2 * HBUF_USH;     // gin2 bf16 [n 512][row RP]

    const int tid = threadIdx.x;
    const int wave = tid >> 6, lane = tid & 63;
    const int l = lane & 15, q = lane >> 4;
    const int jcol = wave * 16 + l;             // this wave's unit column (0..127)
    const int rowbase = blockIdx.x * ROWS;
    const bool active = (wave < 7);             // wave 7 = all-padding units 112..127

    for (int i = tid; i < 2 * HBUF_USH; i += 512) sm[i] = 0;

    // this wave's 16 Whh1 B-frags -> registers (held for all 30 steps)
    short8 bf[4][4];   // [G][kt]
    float u1v[4], wc1v[4];
    floatx4 cst[RGn];  // cell state per rg, rows 4q+r, unit jcol
    float4 xc[RGn];
    if (active) {
        const short8* fr = (const short8*)((const char*)ws + WS_FRAG_OFF);
#pragma unroll
        for (int G = 0; G < 4; ++G)
#pragma unroll
            for (int kt = 0; kt < 4; ++kt)
                bf[G][kt] = fr[((((G << 3) | wave) << 2) + kt) * 64 + lane];
#pragma unroll
        for (int G = 0; G < 4; ++G) {
            u1v[G] = (jcol < Hn) ? ws[G * Hn + jcol] : 0.f;
            wc1v[G] = (jcol < Hn) ? ws[400 + G * Hn + jcol] : 0.f;
        }
#pragma unroll
        for (int rg = 0; rg < RGn; ++rg) {
            cst[rg] = (floatx4){0.f, 0.f, 0.f, 0.f};
            xc[rg] = *(const float4*)(x + rowbase + rg * 16 + 4 * q);
        }
    }

    __syncthreads();   // h buffers zeroed

    // ---- Phase 1: LSTM1, 30 steps, 1 barrier/step ----
    for (int t = 0; t < Tn; ++t) {
        unsigned short* hc = (t & 1) ? hb1 : hb0;
        unsigned short* hn = (t & 1) ? hb0 : hb1;
        if (active) {
            int tn = (t < Tn - 1) ? t + 1 : t;
            float4 xn[RGn];
#pragma unroll
            for (int rg = 0; rg < RGn; ++rg)
                xn[rg] = *(const float4*)(x + tn * Bn + rowbase + rg * 16 + 4 * q);
#pragma unroll
            for (int rg = 0; rg < RGn; ++rg) {
                short8 af[4];   // A[m=l][k=kt*32+q*8+j], rows rg*16+m
#pragma unroll
                for (int kt = 0; kt < 4; ++kt)
                    af[kt] = *(const short8*)(hc + (rg * 16 + l) * KP + kt * 32 + q * 8);
                floatx4 acc[4];
#pragma unroll
                for (int G = 0; G < 4; ++G)
#pragma unroll
                    for (int r = 0; r < 4; ++r)
                        acc[G][r] = fmaf(xc[rg][r], u1v[G], wc1v[G]);
#pragma unroll
                for (int kt = 0; kt < 4; ++kt)
#pragma unroll
                    for (int G = 0; G < 4; ++G)
                        acc[G] = __builtin_amdgcn_mfma_f32_16x16x32_bf16(
                            af[kt], bf[G][kt], acc[G], 0, 0, 0);
#pragma unroll
                for (int r = 0; r < 4; ++r) {
                    float iv = sig_(acc[0][r]);
                    float fv = sig_(acc[1][r]);
                    float gv = tanh_(acc[2][r]);
                    float ov = sig_(acc[3][r]);
                    float cc = fv * cst[rg][r] + iv * gv;
                    cst[rg][r] = cc;
                    hn[(rg * 16 + 4 * q + r) * KP + jcol] = f2bf(ov * tanh_(cc));
                }
            }
#pragma unroll
            for (int rg = 0; rg < RGn; ++rg) xc[rg] = xn[rg];
        }
        __syncthreads();
    }

    // ---- Wih2 frags; gin2 = bias2 + last·Wih2^T parked in LDS (bf16, wave-private n) ----
    if (active) {
        const short8* fr = (const short8*)((const char*)ws + WS_FRAG_OFF + FRAG_BYTES);
#pragma unroll
        for (int G = 0; G < 4; ++G)
#pragma unroll
            for (int kt = 0; kt < 4; ++kt)
                bf[G][kt] = fr[((((G << 3) | wave) << 2) + kt) * 64 + lane];
        unsigned short* hl = hb0;   // last = h after t=29 (t=29 odd -> hn was hb0)
        float bv[4];
#pragma unroll
        for (int G = 0; G < 4; ++G)
            bv[G] = (jcol < Hn) ? (bih2[G * Hn + jcol] + bhh2[G * Hn + jcol]) : 0.f;
#pragma unroll
        for (int rg = 0; rg < RGn; ++rg) {
            short8 af[4];
#pragma unroll
            for (int kt = 0; kt < 4; ++kt)
                af[kt] = *(const short8*)(hl + (rg * 16 + l) * KP + kt * 32 + q * 8);
            floatx4 acc[4];
#pragma unroll
            for (int G = 0; G < 4; ++G)
                acc[G] = (floatx4){bv[G], bv[G], bv[G], bv[G]};
#pragma unroll
            for (int kt = 0; kt < 4; ++kt)
#pragma unroll
                for (int G = 0; G < 4; ++G)
                    acc[G] = __builtin_amdgcn_mfma_f32_16x16x32_bf16(
                        af[kt], bf[G][kt], acc[G], 0, 0, 0);
#pragma unroll
            for (int G = 0; G < 4; ++G) {
                int n = G * 128 + jcol;
                uint2 pk;
                pk.x = (unsigned)f2bf(acc[G][0]) | ((unsigned)f2bf(acc[G][1]) << 16);
                pk.y = (unsigned)f2bf(acc[G][2]) | ((unsigned)f2bf(acc[G][3]) << 16);
                *(uint2*)(g2 + n * RP + rg * 16 + 4 * q) = pk;
            }
        }
        // ---- Whh2 frags ----
        const short8* fr2 = (const short8*)((const char*)ws + WS_FRAG_OFF + 2 * FRAG_BYTES);
#pragma unroll
        for (int G = 0; G < 4; ++G)
#pragma unroll
            for (int kt = 0; kt < 4; ++kt)
                bf[G][kt] = fr2[((((G << 3) | wave) << 2) + kt) * 64 + lane];
    }

    // ---- Phase 2: LSTM2, 7 steps; FC2 via MFMA on waves 0-1 (wave w -> rg w, p = lane&15) ----
    const short8* w2fr = (const short8*)((const char*)ws + WS_W2_OFF);
    floatx4 yfc = (floatx4){0.f, 0.f, 0.f, 0.f};

    for (int ps = 0; ps < Pn; ++ps) {
        int t = Tn + ps;
        unsigned short* hc = (t & 1) ? hb1 : hb0;
        unsigned short* hn = (t & 1) ? hb0 : hb1;
        if (active) {
            const bool dofc = (wave < RGn) && (ps >= 1);   // hc holds h2 of step ps-1
            short8 w2f[4];
            if (dofc) {
#pragma unroll
                for (int kt = 0; kt < 4; ++kt)
                    w2f[kt] = w2fr[((ps - 1) * 4 + kt) * 64 + lane];
            }
#pragma unroll
            for (int rg = 0; rg < RGn; ++rg) {
                short8 af[4];
#pragma unroll
                for (int kt = 0; kt < 4; ++kt)
                    af[kt] = *(const short8*)(hc + (rg * 16 + l) * KP + kt * 32 + q * 8);
                if (dofc && rg == wave) {
#pragma unroll
                    for (int kt = 0; kt < 4; ++kt)
                        yfc = __builtin_amdgcn_mfma_f32_16x16x32_bf16(af[kt], w2f[kt], yfc, 0, 0, 0);
                }
                floatx4 acc[4];
#pragma unroll
                for (int G = 0; G < 4; ++G) {
                    int n = G * 128 + jcol;
                    uint2 pk = *(const uint2*)(g2 + n * RP + rg * 16 + 4 * q);
                    acc[G][0] = __uint_as_float(pk.x << 16);
                    acc[G][1] = __uint_as_float(pk.x & 0xFFFF0000u);
                    acc[G][2] = __uint_as_float(pk.y << 16);
                    acc[G][3] = __uint_as_float(pk.y & 0xFFFF0000u);
                }
#pragma unroll
                for (int kt = 0; kt < 4; ++kt)
#pragma unroll
                    for (int G = 0; G < 4; ++G)
                        acc[G] = __builtin_amdgcn_mfma_f32_16x16x32_bf16(
                            af[kt], bf[G][kt], acc[G], 0, 0, 0);
#pragma unroll
                for (int r = 0; r < 4; ++r) {
                    float iv = sig_(acc[0][r]);
                    float fv = sig_(acc[1][r]);
                    float gv = tanh_(acc[2][r]);
                    float ov = sig_(acc[3][r]);
                    float cc = fv * cst[rg][r] + iv * gv;
                    cst[rg][r] = cc;
                    hn[(rg * 16 + 4 * q + r) * KP + jcol] = f2bf(ov * tanh_(cc));   // ps=6 too (final FC2)
                }
            }
        }
        __syncthreads();
    }

    // ---- final FC2 for h2 of ps=6 (t=36 even -> hn=hb1), then bias+sigmoid+store ----
    if (wave < RGn) {
        short8 w2f[4], af[4];
#pragma unroll
        for (int kt = 0; kt < 4; ++kt) {
            w2f[kt] = w2fr[(6 * 4 + kt) * 64 + lane];
            af[kt] = *(const short8*)(hb1 + (wave * 16 + l) * KP + kt * 32 + q * 8);
        }
#pragma unroll
        for (int kt = 0; kt < 4; ++kt)
            yfc = __builtin_amdgcn_mfma_f32_16x16x32_bf16(af[kt], w2f[kt], yfc, 0, 0, 0);
        if (l < Pn) {
            float bias = b2[l];
#pragma unroll
            for (int r = 0; r < 4; ++r)
                out[(rowbase + wave * 16 + 4 * q + r) * Pn + l] = sig_(yfc[r] + bias);
        }
    }
}

extern "C" void kernel_launch(void* const* d_in, const int* in_sizes, int n_in,
                              void* d_out, int out_size, void* d_ws, size_t ws_size,
                              hipStream_t stream) {
    const float* x    = (const float*)d_in[0];
    const float* W1   = (const float*)d_in[1];
    const float* b1   = (const float*)d_in[2];
    const float* Wih1 = (const float*)d_in[3];
    const float* Whh1 = (const float*)d_in[4];
    const float* bih1 = (const float*)d_in[5];
    const float* bhh1 = (const float*)d_in[6];
    const float* Wih2 = (const float*)d_in[7];
    const float* Whh2 = (const float*)d_in[8];
    const float* bih2 = (const float*)d_in[9];
    const float* bhh2 = (const float*)d_in[10];
    const float* W2   = (const float*)d_in[11];
    const float* b2   = (const float*)d_in[12];
    float* out = (float*)d_out;
    float* ws  = (float*)d_ws;

    (void)hipFuncSetAttribute((const void*)lstm_fused,
                              hipFuncAttributeMaxDynamicSharedMemorySize, SMEM_BYTES);

    setup_kernel<<<PACK_BLOCKS + 2, 256, 0, stream>>>(W1, b1, Wih1, bih1, bhh1,
                                                      Whh1, Wih2, Whh2, W2, ws);
    lstm_fused<<<Bn / ROWS, 512, SMEM_BYTES, stream>>>(x, ws, bih2, bhh2, b2, out);
}

// Round 2
// 224.310 us; speedup vs baseline: 2.4642x; 2.4642x over previous
//
#include <hip/hip_runtime.h>
#include <math.h>

// Problem constants
#define Tn 30
#define Bn 16384
#define Hn 100
#define Pn 7

// Tiling: gates padded 100->128 units => N=512 (32 n-tiles); K padded 100->128 (4 k-tiles of 32).
// 32 rows/block (grid 512) => LDS 54272 B/block => 2 blocks/CU (4 waves/SIMD) for latency hiding.
// __launch_bounds__(512, 2): VGPR cap 128 (arg=4 capped at 64 -> catastrophic spill, round-1 lesson).
// 8 waves/block; wave w owns unit-block ag=w (16 units, all 4 gates); wave 7 is pure padding -> skipped.
// B-fragments (16/wave) live in registers; h double-buffered in LDS; 1 barrier/step.
#define ROWS 32           // rows per block
#define RGn 2             // row-groups of 16
#define KP 136            // h row pitch (ushorts); 272B -> 16B-aligned A-frag reads
#define RP 36             // gin2 row pitch (ushorts): 32 rows + 4 pad
#define NFRAG 128         // B-frags per matrix (32 nt x 4 kt)
#define FRAG_BYTES (NFRAG * 64 * 16)   // 131072 per matrix
#define WS_FRAG_OFF 4096
#define WS_W2_OFF (WS_FRAG_OFF + 3 * FRAG_BYTES)     // 28 W2 frags (7 ps x 4 kt)
#define HBUF_USH (ROWS * KP)                         // 4352
#define SMEM_BYTES (2 * HBUF_USH * 2 + 512 * RP * 2) // 17408 + 36864 = 54272

#define PACK_BLOCKS 103   // (3*128*64 + 28*64)/256

typedef __attribute__((ext_vector_type(8))) short short8;   // 8 bf16 (4 VGPRs)
typedef __attribute__((ext_vector_type(4))) float floatx4;  // MFMA C/D

__device__ __forceinline__ float rcp_(float v) { return __builtin_amdgcn_rcpf(v); }
__device__ __forceinline__ float sig_(float v) { return rcp_(1.0f + __expf(-v)); }
__device__ __forceinline__ float tanh_(float v) { return 1.0f - 2.0f * rcp_(__expf(2.0f * v) + 1.0f); }
__device__ __forceinline__ unsigned short f2bf(float v) {
    unsigned int u = __float_as_uint(v);
    return (unsigned short)((u + 0x7FFFu + ((u >> 16) & 1u)) >> 16);   // RNE
}

// One launch does both jobs:
//  blocks [0, PACK_BLOCKS): pack the 3 recurrent matrices (400x100) into bf16 B-frag layout
//    (gates padded to 128 units), plus W2 (7 x 700) into 7x4 B-frags with n = p.
//    B[k][n]: n = lane&15, k = (lane>>4)*8 + jj  (16x16x32 bf16 B mapping, HW-verified).
//  blocks [PACK_BLOCKS, PACK_BLOCKS+2): ws[0..399] = u1[j] = Wih1[j,:]·W1 (rank-1 FC1 fold);
//    ws[400..799] = Wih1[j,:]·b1 + bih1[j] + bhh1[j]
__global__ void setup_kernel(const float* __restrict__ W1,
                             const float* __restrict__ b1,
                             const float* __restrict__ Wih1,
                             const float* __restrict__ bih1,
                             const float* __restrict__ bhh1,
                             const float* __restrict__ Whh1,
                             const float* __restrict__ Wih2,
                             const float* __restrict__ Whh2,
                             const float* __restrict__ W2,
                             float* __restrict__ ws) {
    if (blockIdx.x >= PACK_BLOCKS) {
        int j = (blockIdx.x - PACK_BLOCKS) * 256 + threadIdx.x;
        if (j < 400) {
            float u = 0.f, w = 0.f;
            for (int k = 0; k < Hn; ++k) {
                float a = Wih1[j * Hn + k];
                u += a * W1[k];
                w += a * b1[k];
            }
            ws[j] = u;
            ws[400 + j] = w + bih1[j] + bhh1[j];
        }
        return;
    }
    int gid = blockIdx.x * 256 + threadIdx.x;   // 3*128*64 + 28*64 = 26368
    int lane = gid & 63;
    int l = lane & 15, q = lane >> 4;
    unsigned short hh[8];
    uint4 u;
    if (gid < 3 * NFRAG * 64) {
        int mat = gid / (NFRAG * 64);
        int f = (gid % (NFRAG * 64)) >> 6;
        int nt = f >> 2, kt = f & 3;
        int G = nt >> 3, ag = nt & 7;
        int j = ag * 16 + l;
        const float* W = (mat == 0) ? Whh1 : (mat == 1) ? Wih2 : Whh2;
        const float* wrow = W + (G * Hn + (j < Hn ? j : 0)) * Hn;
        int kbase = kt * 32 + q * 8;
#pragma unroll
        for (int jj = 0; jj < 8; ++jj) {
            int k = kbase + jj;
            hh[jj] = (j < Hn && k < Hn) ? f2bf(wrow[k]) : (unsigned short)0;
        }
        u.x = (unsigned)hh[0] | ((unsigned)hh[1] << 16);
        u.y = (unsigned)hh[2] | ((unsigned)hh[3] << 16);
        u.z = (unsigned)hh[4] | ((unsigned)hh[5] << 16);
        u.w = (unsigned)hh[6] | ((unsigned)hh[7] << 16);
        ((uint4*)((char*)ws + WS_FRAG_OFF + mat * FRAG_BYTES))[f * 64 + lane] = u;
    } else {
        int t = gid - 3 * NFRAG * 64;           // 0..1791
        int f = t >> 6;                         // 0..27 = ps*4 + kt
        int ps = f >> 2, kt = f & 3;
        int kbase = kt * 32 + q * 8;
#pragma unroll
        for (int jj = 0; jj < 8; ++jj) {
            int k = kbase + jj;
            hh[jj] = (l < Pn && k < Hn) ? f2bf(W2[l * (Pn * Hn) + ps * Hn + k])
                                        : (unsigned short)0;
        }
        u.x = (unsigned)hh[0] | ((unsigned)hh[1] << 16);
        u.y = (unsigned)hh[2] | ((unsigned)hh[3] << 16);
        u.z = (unsigned)hh[4] | ((unsigned)hh[5] << 16);
        u.w = (unsigned)hh[6] | ((unsigned)hh[7] << 16);
        ((uint4*)((char*)ws + WS_W2_OFF))[f * 64 + lane] = u;
    }
}

__global__ __launch_bounds__(512, 2) void lstm_fused(
    const float* __restrict__ x,     // (T,B)
    const float* __restrict__ ws,    // u1/wc1 + packed frags
    const float* __restrict__ bih2,
    const float* __restrict__ bhh2,
    const float* __restrict__ b2,    // (7,)
    float* __restrict__ out)         // (B,7)
{
    extern __shared__ unsigned short sm[];
    unsigned short* hb0 = sm;                   // h double buffer [row ROWS][k KP]
    unsigned short* hb1 = sm + HBUF_USH;
    unsigned short* g2 = sm + 2 * HBUF_USH;     // gin2 bf16 [n 512][row RP]

    const int tid = threadIdx.x;
    const int wave = tid >> 6, lane = tid & 63;
    const int l = lane & 15, q = lane >> 4;
    const int jcol = wave * 16 + l;             // this wave's unit column (0..127)
    const int rowbase = blockIdx.x * ROWS;
    const bool active = (wave < 7);             // wave 7 = all-padding units 112..127

    for (int i = tid; i < 2 * HBUF_USH; i += 512) sm[i] = 0;

    // this wave's 16 Whh1 B-frags -> registers (held for all 30 steps)
    short8 bf[4][4];   // [G][kt]
    float u1v[4], wc1v[4];
    floatx4 cst[RGn];  // cell state per rg, rows 4q+r, unit jcol
    float4 xc[RGn];
    if (active) {
        const short8* fr = (const short8*)((const char*)ws + WS_FRAG_OFF);
#pragma unroll
        for (int G = 0; G < 4; ++G)
#pragma unroll
            for (int kt = 0; kt < 4; ++kt)
                bf[G][kt] = fr[((((G << 3) | wave) << 2) + kt) * 64 + lane];
#pragma unroll
        for (int G = 0; G < 4; ++G) {
            u1v[G] = (jcol < Hn) ? ws[G * Hn + jcol] : 0.f;
            wc1v[G] = (jcol < Hn) ? ws[400 + G * Hn + jcol] : 0.f;
        }
#pragma unroll
        for (int rg = 0; rg < RGn; ++rg) {
            cst[rg] = (floatx4){0.f, 0.f, 0.f, 0.f};
            xc[rg] = *(const float4*)(x + rowbase + rg * 16 + 4 * q);
        }
    }

    __syncthreads();   // h buffers zeroed

    // ---- Phase 1: LSTM1, 30 steps, 1 barrier/step ----
    for (int t = 0; t < Tn; ++t) {
        unsigned short* hc = (t & 1) ? hb1 : hb0;
        unsigned short* hn = (t & 1) ? hb0 : hb1;
        if (active) {
            int tn = (t < Tn - 1) ? t + 1 : t;
            float4 xn[RGn];
#pragma unroll
            for (int rg = 0; rg < RGn; ++rg)
                xn[rg] = *(const float4*)(x + tn * Bn + rowbase + rg * 16 + 4 * q);
#pragma unroll
            for (int rg = 0; rg < RGn; ++rg) {
                short8 af[4];   // A[m=l][k=kt*32+q*8+j], rows rg*16+m
#pragma unroll
                for (int kt = 0; kt < 4; ++kt)
                    af[kt] = *(const short8*)(hc + (rg * 16 + l) * KP + kt * 32 + q * 8);
                floatx4 acc[4];
#pragma unroll
                for (int G = 0; G < 4; ++G)
#pragma unroll
                    for (int r = 0; r < 4; ++r)
                        acc[G][r] = fmaf(xc[rg][r], u1v[G], wc1v[G]);
#pragma unroll
                for (int kt = 0; kt < 4; ++kt)
#pragma unroll
                    for (int G = 0; G < 4; ++G)
                        acc[G] = __builtin_amdgcn_mfma_f32_16x16x32_bf16(
                            af[kt], bf[G][kt], acc[G], 0, 0, 0);
#pragma unroll
                for (int r = 0; r < 4; ++r) {
                    float iv = sig_(acc[0][r]);
                    float fv = sig_(acc[1][r]);
                    float gv = tanh_(acc[2][r]);
                    float ov = sig_(acc[3][r]);
                    float cc = fv * cst[rg][r] + iv * gv;
                    cst[rg][r] = cc;
                    hn[(rg * 16 + 4 * q + r) * KP + jcol] = f2bf(ov * tanh_(cc));
                }
            }
#pragma unroll
            for (int rg = 0; rg < RGn; ++rg) xc[rg] = xn[rg];
        }
        __syncthreads();
    }

    // ---- Wih2 frags; gin2 = bias2 + last·Wih2^T parked in LDS (bf16, wave-private n) ----
    if (active) {
        const short8* fr = (const short8*)((const char*)ws + WS_FRAG_OFF + FRAG_BYTES);
#pragma unroll
        for (int G = 0; G < 4; ++G)
#pragma unroll
            for (int kt = 0; kt < 4; ++kt)
                bf[G][kt] = fr[((((G << 3) | wave) << 2) + kt) * 64 + lane];
        unsigned short* hl = hb0;   // last = h after t=29 (t=29 odd -> hn was hb0)
        float bv[4];
#pragma unroll
        for (int G = 0; G < 4; ++G)
            bv[G] = (jcol < Hn) ? (bih2[G * Hn + jcol] + bhh2[G * Hn + jcol]) : 0.f;
#pragma unroll
        for (int rg = 0; rg < RGn; ++rg) {
            short8 af[4];
#pragma unroll
            for (int kt = 0; kt < 4; ++kt)
                af[kt] = *(const short8*)(hl + (rg * 16 + l) * KP + kt * 32 + q * 8);
            floatx4 acc[4];
#pragma unroll
            for (int G = 0; G < 4; ++G)
                acc[G] = (floatx4){bv[G], bv[G], bv[G], bv[G]};
#pragma unroll
            for (int kt = 0; kt < 4; ++kt)
#pragma unroll
                for (int G = 0; G < 4; ++G)
                    acc[G] = __builtin_amdgcn_mfma_f32_16x16x32_bf16(
                        af[kt], bf[G][kt], acc[G], 0, 0, 0);
#pragma unroll
            for (int G = 0; G < 4; ++G) {
                int n = G * 128 + jcol;
                uint2 pk;
                pk.x = (unsigned)f2bf(acc[G][0]) | ((unsigned)f2bf(acc[G][1]) << 16);
                pk.y = (unsigned)f2bf(acc[G][2]) | ((unsigned)f2bf(acc[G][3]) << 16);
                *(uint2*)(g2 + n * RP + rg * 16 + 4 * q) = pk;
            }
        }
        // ---- Whh2 frags ----
        const short8* fr2 = (const short8*)((const char*)ws + WS_FRAG_OFF + 2 * FRAG_BYTES);
#pragma unroll
        for (int G = 0; G < 4; ++G)
#pragma unroll
            for (int kt = 0; kt < 4; ++kt)
                bf[G][kt] = fr2[((((G << 3) | wave) << 2) + kt) * 64 + lane];
    }

    // ---- Phase 2: LSTM2, 7 steps; FC2 via MFMA on waves 0-1 (wave w -> rg w, p = lane&15) ----
    const short8* w2fr = (const short8*)((const char*)ws + WS_W2_OFF);
    floatx4 yfc = (floatx4){0.f, 0.f, 0.f, 0.f};

    for (int ps = 0; ps < Pn; ++ps) {
        int t = Tn + ps;
        unsigned short* hc = (t & 1) ? hb1 : hb0;
        unsigned short* hn = (t & 1) ? hb0 : hb1;
        if (active) {
            const bool dofc = (wave < RGn) && (ps >= 1);   // hc holds h2 of step ps-1
            short8 w2f[4];
            if (dofc) {
#pragma unroll
                for (int kt = 0; kt < 4; ++kt)
                    w2f[kt] = w2fr[((ps - 1) * 4 + kt) * 64 + lane];
            }
#pragma unroll
            for (int rg = 0; rg < RGn; ++rg) {
                short8 af[4];
#pragma unroll
                for (int kt = 0; kt < 4; ++kt)
                    af[kt] = *(const short8*)(hc + (rg * 16 + l) * KP + kt * 32 + q * 8);
                if (dofc && rg == wave) {
#pragma unroll
                    for (int kt = 0; kt < 4; ++kt)
                        yfc = __builtin_amdgcn_mfma_f32_16x16x32_bf16(af[kt], w2f[kt], yfc, 0, 0, 0);
                }
                floatx4 acc[4];
#pragma unroll
                for (int G = 0; G < 4; ++G) {
                    int n = G * 128 + jcol;
                    uint2 pk = *(const uint2*)(g2 + n * RP + rg * 16 + 4 * q);
                    acc[G][0] = __uint_as_float(pk.x << 16);
                    acc[G][1] = __uint_as_float(pk.x & 0xFFFF0000u);
                    acc[G][2] = __uint_as_float(pk.y << 16);
                    acc[G][3] = __uint_as_float(pk.y & 0xFFFF0000u);
                }
#pragma unroll
                for (int kt = 0; kt < 4; ++kt)
#pragma unroll
                    for (int G = 0; G < 4; ++G)
                        acc[G] = __builtin_amdgcn_mfma_f32_16x16x32_bf16(
                            af[kt], bf[G][kt], acc[G], 0, 0, 0);
#pragma unroll
                for (int r = 0; r < 4; ++r) {
                    float iv = sig_(acc[0][r]);
                    float fv = sig_(acc[1][r]);
                    float gv = tanh_(acc[2][r]);
                    float ov = sig_(acc[3][r]);
                    float cc = fv * cst[rg][r] + iv * gv;
                    cst[rg][r] = cc;
                    hn[(rg * 16 + 4 * q + r) * KP + jcol] = f2bf(ov * tanh_(cc));   // ps=6 too (final FC2)
                }
            }
        }
        __syncthreads();
    }

    // ---- final FC2 for h2 of ps=6 (t=36 even -> hn=hb1), then bias+sigmoid+store ----
    if (wave < RGn) {
        short8 w2f[4], af[4];
#pragma unroll
        for (int kt = 0; kt < 4; ++kt) {
            w2f[kt] = w2fr[(6 * 4 + kt) * 64 + lane];
            af[kt] = *(const short8*)(hb1 + (wave * 16 + l) * KP + kt * 32 + q * 8);
        }
#pragma unroll
        for (int kt = 0; kt < 4; ++kt)
            yfc = __builtin_amdgcn_mfma_f32_16x16x32_bf16(af[kt], w2f[kt], yfc, 0, 0, 0);
        if (l < Pn) {
            float bias = b2[l];
#pragma unroll
            for (int r = 0; r < 4; ++r)
                out[(rowbase + wave * 16 + 4 * q + r) * Pn + l] = sig_(yfc[r] + bias);
        }
    }
}

extern "C" void kernel_launch(void* const* d_in, const int* in_sizes, int n_in,
                              void* d_out, int out_size, void* d_ws, size_t ws_size,
                              hipStream_t stream) {
    const float* x    = (const float*)d_in[0];
    const float* W1   = (const float*)d_in[1];
    const float* b1   = (const float*)d_in[2];
    const float* Wih1 = (const float*)d_in[3];
    const float* Whh1 = (const float*)d_in[4];
    const float* bih1 = (const float*)d_in[5];
    const float* bhh1 = (const float*)d_in[6];
    const float* Wih2 = (const float*)d_in[7];
    const float* Whh2 = (const float*)d_in[8];
    const float* bih2 = (const float*)d_in[9];
    const float* bhh2 = (const float*)d_in[10];
    const float* W2   = (const float*)d_in[11];
    const float* b2   = (const float*)d_in[12];
    float* out = (float*)d_out;
    float* ws  = (float*)d_ws;

    (void)hipFuncSetAttribute((const void*)lstm_fused,
                              hipFuncAttributeMaxDynamicSharedMemorySize, SMEM_BYTES);

    setup_kernel<<<PACK_BLOCKS + 2, 256, 0, stream>>>(W1, b1, Wih1, bih1, bhh1,
                                                      Whh1, Wih2, Whh2, W2, ws);
    lstm_fused<<<Bn / ROWS, 512, SMEM_BYTES, stream>>>(x, ws, bih2, bhh2, b2, out);
}

// Round 3
// 210.222 us; speedup vs baseline: 2.6293x; 1.0670x over previous
//
#include <hip/hip_runtime.h>
#include <math.h>

// Problem constants
#define Tn 30
#define Bn 16384
#define Hn 100
#define Pn 7

// Tiling: gates padded 100->128 units => N=512 (32 n-tiles); K padded 100->128 (4 k-tiles of 32).
// K slots 100/101 carry the FC1 fold: A[k=100]=x_t(row), A[k=101]=1.0 (maintained by wave 6,
// whose unit columns 100..111 are padding); Whh1 B rows 100/101 hold u1[j]/wc1[j].
// => no u1v/wc1v/xc/xn arch registers, acc init = zero.
// 32 rows/block (grid 512), 8 waves; wave w owns units [16w,16w+16); wave 7 idle in phase 1,
// runs FC2 in phase 2. __launch_bounds__(512,4): 128 total regs/wave (64 arch + 64 acc for bf)
// => 2 blocks/CU = 4 waves/SIMD. LDS 58112 B/block (h dbuf + gin2 + x slice).
#define ROWS 32           // rows per block
#define RGn 2             // row-groups of 16
#define KP 136            // h row pitch (ushorts); 272B -> 16B-aligned A-frag reads
#define RP 36             // gin2 row pitch (ushorts): 32 rows + 4 pad
#define NFRAG 128         // B-frags per matrix (32 nt x 4 kt)
#define FRAG_BYTES (NFRAG * 64 * 16)   // 131072 per matrix
#define WS_W2_OFF (3 * FRAG_BYTES)     // 28 W2 frags (7 ps x 4 kt)
#define HBUF_USH (ROWS * KP)           // 4352
#define G2_USH (512 * RP)              // 18432
#define XL_USH_OFF (2 * HBUF_USH + G2_USH)            // 27136 ushorts
#define SMEM_BYTES (XL_USH_OFF * 2 + Tn * ROWS * 4)   // 54272 + 3840 = 58112

#define PACK_BLOCKS 103   // (3*128*64 + 28*64)/256 exactly

typedef __attribute__((ext_vector_type(8))) short short8;   // 8 bf16 (4 VGPRs)
typedef __attribute__((ext_vector_type(4))) float floatx4;  // MFMA C/D

__device__ __forceinline__ float rcp_(float v) { return __builtin_amdgcn_rcpf(v); }
__device__ __forceinline__ float sig_(float v) { return rcp_(1.0f + __expf(-v)); }
__device__ __forceinline__ float tanh_(float v) { return 1.0f - 2.0f * rcp_(__expf(2.0f * v) + 1.0f); }
__device__ __forceinline__ unsigned short f2bf(float v) {
    unsigned int u = __float_as_uint(v);
    return (unsigned short)((u + 0x7FFFu + ((u >> 16) & 1u)) >> 16);   // RNE
}

// Pack the 3 recurrent matrices (400x100) into bf16 B-frag layout (gates padded to 128 units),
// with the bias/FC1 folds in padded K rows:
//   mat 0 (Whh1): k=100 -> u1[j] = Wih1[j,:]·W1 ; k=101 -> wc1[j] = Wih1[j,:]·b1 + bih1[j] + bhh1[j]
//   mat 1 (Wih2): k=101 -> bih2[j] + bhh2[j]
//   W2 frags:     k=101 && ps==6 -> b2[p]   (A k=101 is 1.0 every step; add bias exactly once)
// B[k][n]: n = lane&15, k = (lane>>4)*8 + jj  (16x16x32 bf16 B mapping, HW-verified).
__global__ void setup_kernel(const float* __restrict__ W1,
                             const float* __restrict__ b1,
                             const float* __restrict__ Wih1,
                             const float* __restrict__ bih1,
                             const float* __restrict__ bhh1,
                             const float* __restrict__ bih2,
                             const float* __restrict__ bhh2,
                             const float* __restrict__ Whh1,
                             const float* __restrict__ Wih2,
                             const float* __restrict__ Whh2,
                             const float* __restrict__ W2,
                             const float* __restrict__ b2,
                             float* __restrict__ ws) {
    int gid = blockIdx.x * 256 + threadIdx.x;   // 3*128*64 + 28*64 = 26368
    int lane = gid & 63;
    int l = lane & 15, q = lane >> 4;
    unsigned short hh[8];
    uint4 u;
    if (gid < 3 * NFRAG * 64) {
        int mat = gid / (NFRAG * 64);
        int f = (gid % (NFRAG * 64)) >> 6;
        int nt = f >> 2, kt = f & 3;
        int G = nt >> 3, ag = nt & 7;
        int j = ag * 16 + l;                    // unit within gate
        int row = G * Hn + (j < Hn ? j : 0);    // row of the 400-row weight matrices
        const float* W = (mat == 0) ? Whh1 : (mat == 1) ? Wih2 : Whh2;
        const float* wrow = W + row * Hn;
        float u1 = 0.f, wc1 = 0.f;
        if (mat == 0 && kt == 3 && q == 0 && j < Hn) {   // lanes producing k=100/101
            for (int k = 0; k < Hn; ++k) {
                float a = Wih1[row * Hn + k];
                u1 += a * W1[k];
                wc1 += a * b1[k];
            }
            wc1 += bih1[row] + bhh1[row];
        }
        int kbase = kt * 32 + q * 8;
#pragma unroll
        for (int jj = 0; jj < 8; ++jj) {
            int k = kbase + jj;
            unsigned short v = 0;
            if (j < Hn) {
                if (k < Hn) v = f2bf(wrow[k]);
                else if (mat == 0 && k == 100) v = f2bf(u1);
                else if (mat == 0 && k == 101) v = f2bf(wc1);
                else if (mat == 1 && k == 101) v = f2bf(bih2[row] + bhh2[row]);
            }
            hh[jj] = v;
        }
        u.x = (unsigned)hh[0] | ((unsigned)hh[1] << 16);
        u.y = (unsigned)hh[2] | ((unsigned)hh[3] << 16);
        u.z = (unsigned)hh[4] | ((unsigned)hh[5] << 16);
        u.w = (unsigned)hh[6] | ((unsigned)hh[7] << 16);
        ((uint4*)((char*)ws + mat * FRAG_BYTES))[f * 64 + lane] = u;
    } else {
        int t = gid - 3 * NFRAG * 64;           // 0..1791
        int f = t >> 6;                         // 0..27 = ps*4 + kt
        int ps = f >> 2, kt = f & 3;
        int kbase = kt * 32 + q * 8;
#pragma unroll
        for (int jj = 0; jj < 8; ++jj) {
            int k = kbase + jj;
            unsigned short v = 0;
            if (l < Pn) {
                if (k < Hn) v = f2bf(W2[l * (Pn * Hn) + ps * Hn + k]);
                else if (k == 101 && ps == 6) v = f2bf(b2[l]);
            }
            hh[jj] = v;
        }
        u.x = (unsigned)hh[0] | ((unsigned)hh[1] << 16);
        u.y = (unsigned)hh[2] | ((unsigned)hh[3] << 16);
        u.z = (unsigned)hh[4] | ((unsigned)hh[5] << 16);
        u.w = (unsigned)hh[6] | ((unsigned)hh[7] << 16);
        ((uint4*)((char*)ws + WS_W2_OFF))[f * 64 + lane] = u;
    }
}

__global__ __launch_bounds__(512, 4) void lstm_fused(
    const float* __restrict__ x,     // (T,B)
    const float* __restrict__ ws,    // packed frags (+folds)
    float* __restrict__ out)         // (B,7)
{
    extern __shared__ unsigned short sm[];
    unsigned short* hb0 = sm;                   // h double buffer [row ROWS][k KP]
    unsigned short* hb1 = sm + HBUF_USH;
    unsigned short* g2 = sm + 2 * HBUF_USH;     // gin2 bf16 [n 512][row RP]
    float* xl = (float*)(sm + XL_USH_OFF);      // x slice [t 30][row 32]

    const int tid = threadIdx.x;
    const int wave = tid >> 6, lane = tid & 63;
    const int l = lane & 15, q = lane >> 4;
    const int jcol = wave * 16 + l;             // this wave's unit column (0..127)
    const int rowbase = blockIdx.x * ROWS;
    const bool active = (wave < 7);             // wave 7: padding units; does FC2 in phase 2

    for (int i = tid; i < 2 * HBUF_USH; i += 512) sm[i] = 0;
    for (int i = tid; i < Tn * ROWS; i += 512)
        xl[i] = x[(i >> 5) * Bn + rowbase + (i & 31)];
    __syncthreads();   // zeroing done before seeding (different writers)
    if (tid < ROWS) {
        hb0[tid * KP + 100] = f2bf(x[rowbase + tid]);   // x_0 in K slot 100
        hb0[tid * KP + 101] = (unsigned short)0x3F80;   // 1.0 in K slot 101
    }

    // this wave's 16 Whh1 B-frags -> registers (held for all 30 steps; AGPR-resident)
    short8 bf[4][4];   // [G][kt]
    floatx4 cst[RGn];  // cell state per rg, rows 4q+r, unit jcol
    const floatx4 zro = (floatx4){0.f, 0.f, 0.f, 0.f};
    if (active) {
        const short8* fr = (const short8*)ws;
#pragma unroll
        for (int G = 0; G < 4; ++G)
#pragma unroll
            for (int kt = 0; kt < 4; ++kt)
                bf[G][kt] = fr[((((G << 3) | wave) << 2) + kt) * 64 + lane];
#pragma unroll
        for (int rg = 0; rg < RGn; ++rg) cst[rg] = zro;
    }
    __syncthreads();   // h buffers ready (zero + seed)

    // ---- Phase 1: LSTM1, 30 steps, 1 barrier/step ----
    for (int t = 0; t < Tn; ++t) {
        const unsigned short* hc = (t & 1) ? hb1 : hb0;
        unsigned short* hn = (t & 1) ? hb0 : hb1;
        if (active) {
            int tn = (t < Tn - 1) ? t + 1 : t;
#pragma unroll
            for (int rg = 0; rg < RGn; ++rg) {
                short8 af[4];   // A[m=l][k=kt*32+q*8+j], rows rg*16+m
#pragma unroll
                for (int kt = 0; kt < 4; ++kt)
                    af[kt] = *(const short8*)(hc + (rg * 16 + l) * KP + kt * 32 + q * 8);
                floatx4 acc[4];
#pragma unroll
                for (int G = 0; G < 4; ++G)
                    acc[G] = __builtin_amdgcn_mfma_f32_16x16x32_bf16(af[0], bf[G][0], zro, 0, 0, 0);
#pragma unroll
                for (int kt = 1; kt < 4; ++kt)
#pragma unroll
                    for (int G = 0; G < 4; ++G)
                        acc[G] = __builtin_amdgcn_mfma_f32_16x16x32_bf16(
                            af[kt], bf[G][kt], acc[G], 0, 0, 0);
                float4 xn4;
                if (wave == 6)
                    xn4 = *(const float4*)(xl + tn * ROWS + rg * 16 + 4 * q);
#pragma unroll
                for (int r = 0; r < 4; ++r) {
                    float iv = sig_(acc[0][r]);
                    float fv = sig_(acc[1][r]);
                    float gv = tanh_(acc[2][r]);
                    float ov = sig_(acc[3][r]);
                    float cc = fv * cst[rg][r] + iv * gv;
                    cst[rg][r] = cc;
                    unsigned short us = f2bf(ov * tanh_(cc));
                    if (wave == 6)   // cols 100..111 are padding: carry x_{t+1} and 1.0
                        us = (l < 4) ? us
                           : (l == 4) ? f2bf(xn4[r])
                           : (l == 5) ? (unsigned short)0x3F80 : (unsigned short)0;
                    hn[(rg * 16 + 4 * q + r) * KP + jcol] = us;
                }
            }
        }
        __syncthreads();
    }

    // ---- Wih2 frags; gin2 = (bih2+bhh2 fold) + last·Wih2^T parked in LDS (wave-private n) ----
    if (active) {
        const short8* fr = (const short8*)((const char*)ws + FRAG_BYTES);
#pragma unroll
        for (int G = 0; G < 4; ++G)
#pragma unroll
            for (int kt = 0; kt < 4; ++kt)
                bf[G][kt] = fr[((((G << 3) | wave) << 2) + kt) * 64 + lane];
        const unsigned short* hl = hb0;   // last = h after t=29 (t=29 odd -> hn was hb0)
#pragma unroll
        for (int rg = 0; rg < RGn; ++rg) {
            short8 af[4];
#pragma unroll
            for (int kt = 0; kt < 4; ++kt)
                af[kt] = *(const short8*)(hl + (rg * 16 + l) * KP + kt * 32 + q * 8);
            floatx4 acc[4];
#pragma unroll
            for (int G = 0; G < 4; ++G)
                acc[G] = __builtin_amdgcn_mfma_f32_16x16x32_bf16(af[0], bf[G][0], zro, 0, 0, 0);
#pragma unroll
            for (int kt = 1; kt < 4; ++kt)
#pragma unroll
                for (int G = 0; G < 4; ++G)
                    acc[G] = __builtin_amdgcn_mfma_f32_16x16x32_bf16(
                        af[kt], bf[G][kt], acc[G], 0, 0, 0);
#pragma unroll
            for (int G = 0; G < 4; ++G) {
                int n = G * 128 + jcol;
                uint2 pk;
                pk.x = (unsigned)f2bf(acc[G][0]) | ((unsigned)f2bf(acc[G][1]) << 16);
                pk.y = (unsigned)f2bf(acc[G][2]) | ((unsigned)f2bf(acc[G][3]) << 16);
                *(uint2*)(g2 + n * RP + rg * 16 + 4 * q) = pk;   // same wave reads it back
            }
        }
        // ---- Whh2 frags ----
        const short8* fr2 = (const short8*)((const char*)ws + 2 * FRAG_BYTES);
#pragma unroll
        for (int G = 0; G < 4; ++G)
#pragma unroll
            for (int kt = 0; kt < 4; ++kt)
                bf[G][kt] = fr2[((((G << 3) | wave) << 2) + kt) * 64 + lane];
    }

    // ---- Phase 2: LSTM2, 7 steps; FC2 runs on the otherwise-idle wave 7 ----
    const short8* w2fr = (const short8*)((const char*)ws + WS_W2_OFF);
    floatx4 yfc[RGn];
    if (wave == 7) {
#pragma unroll
        for (int rg = 0; rg < RGn; ++rg) yfc[rg] = zro;
    }

    for (int ps = 0; ps < Pn; ++ps) {
        int t = Tn + ps;
        const unsigned short* hc = (t & 1) ? hb1 : hb0;
        unsigned short* hn = (t & 1) ? hb0 : hb1;
        if (wave == 7) {
            if (ps >= 1) {   // hc holds h2 of step ps-1
                short8 w2f[4];
#pragma unroll
                for (int kt = 0; kt < 4; ++kt)
                    w2f[kt] = w2fr[((ps - 1) * 4 + kt) * 64 + lane];
#pragma unroll
                for (int rg = 0; rg < RGn; ++rg) {
                    short8 af2[4];
#pragma unroll
                    for (int kt = 0; kt < 4; ++kt)
                        af2[kt] = *(const short8*)(hc + (rg * 16 + l) * KP + kt * 32 + q * 8);
#pragma unroll
                    for (int kt = 0; kt < 4; ++kt)
                        yfc[rg] = __builtin_amdgcn_mfma_f32_16x16x32_bf16(
                            af2[kt], w2f[kt], yfc[rg], 0, 0, 0);
                }
            }
        } else {
#pragma unroll
            for (int rg = 0; rg < RGn; ++rg) {
                short8 af[4];
#pragma unroll
                for (int kt = 0; kt < 4; ++kt)
                    af[kt] = *(const short8*)(hc + (rg * 16 + l) * KP + kt * 32 + q * 8);
                floatx4 acc[4];
#pragma unroll
                for (int G = 0; G < 4; ++G) {
                    int n = G * 128 + jcol;
                    uint2 pk = *(const uint2*)(g2 + n * RP + rg * 16 + 4 * q);
                    acc[G][0] = __uint_as_float(pk.x << 16);
                    acc[G][1] = __uint_as_float(pk.x & 0xFFFF0000u);
                    acc[G][2] = __uint_as_float(pk.y << 16);
                    acc[G][3] = __uint_as_float(pk.y & 0xFFFF0000u);
                }
#pragma unroll
                for (int kt = 0; kt < 4; ++kt)
#pragma unroll
                    for (int G = 0; G < 4; ++G)
                        acc[G] = __builtin_amdgcn_mfma_f32_16x16x32_bf16(
                            af[kt], bf[G][kt], acc[G], 0, 0, 0);
#pragma unroll
                for (int r = 0; r < 4; ++r) {
                    float iv = sig_(acc[0][r]);
                    float fv = sig_(acc[1][r]);
                    float gv = tanh_(acc[2][r]);
                    float ov = sig_(acc[3][r]);
                    float cc = fv * cst[rg][r] + iv * gv;
                    cst[rg][r] = cc;
                    unsigned short us = f2bf(ov * tanh_(cc));
                    if (wave == 6)   // phase 2: keep 1.0 at col 101 (b2 fold), zero pads
                        us = (l < 4) ? us
                           : (l == 5) ? (unsigned short)0x3F80 : (unsigned short)0;
                    hn[(rg * 16 + 4 * q + r) * KP + jcol] = us;   // ps=6 too (final FC2)
                }
            }
        }
        __syncthreads();
    }

    // ---- final FC2 for h2 of ps=6 (t=36 even -> hn=hb1); b2 folded into ps=6 frag k=101 ----
    if (wave == 7) {
        short8 w2f[4];
#pragma unroll
        for (int kt = 0; kt < 4; ++kt)
            w2f[kt] = w2fr[(6 * 4 + kt) * 64 + lane];
#pragma unroll
        for (int rg = 0; rg < RGn; ++rg) {
            short8 af2[4];
#pragma unroll
            for (int kt = 0; kt < 4; ++kt)
                af2[kt] = *(const short8*)(hb1 + (rg * 16 + l) * KP + kt * 32 + q * 8);
#pragma unroll
            for (int kt = 0; kt < 4; ++kt)
                yfc[rg] = __builtin_amdgcn_mfma_f32_16x16x32_bf16(
                    af2[kt], w2f[kt], yfc[rg], 0, 0, 0);
            if (l < Pn) {
#pragma unroll
                for (int r = 0; r < 4; ++r)
                    out[(rowbase + rg * 16 + 4 * q + r) * Pn + l] = sig_(yfc[rg][r]);
            }
        }
    }
}

extern "C" void kernel_launch(void* const* d_in, const int* in_sizes, int n_in,
                              void* d_out, int out_size, void* d_ws, size_t ws_size,
                              hipStream_t stream) {
    const float* x    = (const float*)d_in[0];
    const float* W1   = (const float*)d_in[1];
    const float* b1   = (const float*)d_in[2];
    const float* Wih1 = (const float*)d_in[3];
    const float* Whh1 = (const float*)d_in[4];
    const float* bih1 = (const float*)d_in[5];
    const float* bhh1 = (const float*)d_in[6];
    const float* Wih2 = (const float*)d_in[7];
    const float* Whh2 = (const float*)d_in[8];
    const float* bih2 = (const float*)d_in[9];
    const float* bhh2 = (const float*)d_in[10];
    const float* W2   = (const float*)d_in[11];
    const float* b2   = (const float*)d_in[12];
    float* out = (float*)d_out;
    float* ws  = (float*)d_ws;

    (void)hipFuncSetAttribute((const void*)lstm_fused,
                              hipFuncAttributeMaxDynamicSharedMemorySize, SMEM_BYTES);

    setup_kernel<<<PACK_BLOCKS, 256, 0, stream>>>(W1, b1, Wih1, bih1, bhh1,
                                                  bih2, bhh2, Whh1, Wih2, Whh2, W2, b2, ws);
    lstm_fused<<<Bn / ROWS, 512, SMEM_BYTES, stream>>>(x, ws, out);
}